// Round 8
// baseline (546.770 us; speedup 1.0000x reference)
//
#include <hip/hip_runtime.h>
#include <cstddef>
#include <cstdint>

#define NB   8
#define LQ   1024
#define CH   512
#define HHE  8
#define HDD  64
#define PPM  16
#define LP   1040     // L + P
#define HID  2048

typedef unsigned short ushort_t;
typedef __attribute__((ext_vector_type(8))) short short8;
typedef __attribute__((ext_vector_type(4))) float floatx4;

// ---- workspace layout (float element offsets) ----
static const size_t O_QB   = 0;          // Qb bf16   (2,097,152 fl)
static const size_t O_KB   = 2097152;    // Kb bf16   (2,129,920 fl)
static const size_t O_VB   = 4227072;    // Vb bf16   (2,129,920 fl)
static const size_t O_VT   = 6356992;    // VT bf16   (2,129,920 fl)
static const size_t O_AOB  = 8486912;    // aob bf16  (2,097,152 fl)
static const size_t O_AF   = 10584064;   // abf/fbf fp32 (4,194,304 fl)
// hraw bf16 overlays floats [0 .. 16,777,216) -- all of the above are dead then
static const size_t O_X1B  = 16777216;   // x1b padded bf16 (2,101,248 fl)
static const size_t O_HPAD = 18878464;   // hpad bf16 (8,404,992 fl)
static const size_t O_W1   = 27283456;   // w1 bf16   (3,145,728 fl)
static const size_t O_W2   = 30429184;   // w2 bf16   (1,572,864 fl)
static const size_t O_WO   = 32002048;   // wo bf16   (131,072 fl)
// total 32,133,120 floats = 128.5 MB

__device__ __forceinline__ ushort_t f2bf(float f) {
  uint32_t u = __float_as_uint(f);
  u += 0x7FFFu + ((u >> 16) & 1u);
  return (ushort_t)(u >> 16);
}
__device__ __forceinline__ float bf2f(ushort_t h) {
  return __uint_as_float(((uint32_t)h) << 16);
}

__device__ __forceinline__ void async16(ushort_t* lds, const ushort_t* g) {
  __builtin_amdgcn_global_load_lds(
      (const __attribute__((address_space(1))) void*)g,
      (__attribute__((address_space(3))) void*)lds, 16, 0, 0);
}

// ---------------------------------------------------------------------------
// weight pack to bf16 [oc][k], k = dl*IC + ic; src[oc*K + ic*KD + dl]
// ---------------------------------------------------------------------------
__global__ __launch_bounds__(256) void pack_bf16_kernel(
    const float* __restrict__ src, ushort_t* __restrict__ dst,
    int K, int KD, int icShift)
{
  const int oc = blockIdx.x;
  const int icMask = (1 << icShift) - 1;
  for (int k = threadIdx.x; k < K; k += 256) {
    int ic = k & icMask, dl = k >> icShift;
    dst[(size_t)oc * K + k] = f2bf(src[(size_t)oc * K + ic * KD + dl]);
  }
}

// ---------------------------------------------------------------------------
// Generic bf16 MFMA GEMM, 128x128 tile, BK=32, global_load_lds staging.
// (used for conv1 only; compute-bound shape)
// ---------------------------------------------------------------------------
template<int EPI>
__global__ __launch_bounds__(256, 2) void mfma_gemm(
    const ushort_t* __restrict__ Ab, const ushort_t* __restrict__ Bb,
    int K, int BS, int P, int NOUT,
    const float* __restrict__ bias, const float* __restrict__ res,
    float* __restrict__ outf, ushort_t* __restrict__ outh)
{
  __shared__ ushort_t As[128 * 32];
  __shared__ ushort_t Bs[128 * 32];
  const int t = threadIdx.x;
  const int w = t >> 6, l = t & 63;
  const int m0 = blockIdx.x * 128, n0 = blockIdx.y * 128;

  const int sub = l >> 2;
  const int kc8 = (l & 3) * 8;
  const ushort_t* aptr[2];
  const ushort_t* bptr[2];
  #pragma unroll
  for (int c = 0; c < 2; ++c) {
    int arow = m0 + w * 32 + c * 16 + sub;
    aptr[c] = Ab + (size_t)(arow >> 10) * BS + (size_t)(arow & 1023) * P + kc8;
    int brow = n0 + w * 32 + c * 16 + sub;
    bptr[c] = Bb + (size_t)brow * K + kc8;
  }

  const int wm = w >> 1, wn = w & 1;
  const int lm = l & 15, q = l >> 4;
  floatx4 acc[4][4];
  #pragma unroll
  for (int i = 0; i < 4; ++i)
    #pragma unroll
    for (int j = 0; j < 4; ++j)
      acc[i][j] = (floatx4){0.f, 0.f, 0.f, 0.f};

  const int kIters = K >> 5;
  for (int kt = 0; kt < kIters; ++kt) {
    __syncthreads();
    async16(&As[w * 1024 +   0], aptr[0]);
    async16(&As[w * 1024 + 512], aptr[1]);
    async16(&Bs[w * 1024 +   0], bptr[0]);
    async16(&Bs[w * 1024 + 512], bptr[1]);
    aptr[0] += 32; aptr[1] += 32; bptr[0] += 32; bptr[1] += 32;
    __syncthreads();
    short8 af[4], bf[4];
    #pragma unroll
    for (int i = 0; i < 4; ++i)
      af[i] = *(const short8*)&As[(wm * 64 + i * 16 + lm) * 32 + q * 8];
    #pragma unroll
    for (int i = 0; i < 4; ++i)
      bf[i] = *(const short8*)&Bs[(wn * 64 + i * 16 + lm) * 32 + q * 8];
    #pragma unroll
    for (int i = 0; i < 4; ++i)
      #pragma unroll
      for (int j = 0; j < 4; ++j)
        acc[i][j] = __builtin_amdgcn_mfma_f32_16x16x32_bf16(af[i], bf[j], acc[i][j], 0, 0, 0);
  }

  #pragma unroll
  for (int i = 0; i < 4; ++i) {
    #pragma unroll
    for (int j = 0; j < 4; ++j) {
      const int mbase = m0 + wm * 64 + i * 16 + q * 4;
      const int n = n0 + wn * 64 + j * 16 + lm;
      #pragma unroll
      for (int r = 0; r < 4; ++r) {
        const int m = mbase + r;
        float v = acc[i][j][r];
        if (EPI == 0) {
          outh[(size_t)m * NOUT + n] = f2bf(v);
        } else if (EPI == 1) {
          outf[(size_t)m * NOUT + n] = v + bias[n];
        } else {
          outf[(size_t)m * NOUT + n] = v + bias[n] + res[(size_t)m * NOUT + n];
        }
      }
    }
  }
}

// ---------------------------------------------------------------------------
// 128x64-tile bf16 MFMA GEMM for small-N latency-bound shapes (Wo, conv2).
// 512 blocks at N=512 and 4 blocks/CU (acc is only 2x4 frags) -> wave
// overlap instead of split-K partial traffic. Same staging/frag scheme as
// mfma_gemm; wave w owns rows [w*32, w*32+32) x all 64 cols.
// ---------------------------------------------------------------------------
template<int EPI>
__global__ __launch_bounds__(256, 4) void mfma_gemm_n64(
    const ushort_t* __restrict__ Ab, const ushort_t* __restrict__ Bb,
    int K, int BS, int P, int NOUT,
    const float* __restrict__ bias, const float* __restrict__ res,
    float* __restrict__ outf)
{
  __shared__ ushort_t As[128 * 32];
  __shared__ ushort_t Bs[64 * 32];
  const int t = threadIdx.x;
  const int w = t >> 6, l = t & 63;
  const int m0 = blockIdx.x * 128, n0 = blockIdx.y * 64;

  const int sub = l >> 2;
  const int kc8 = (l & 3) * 8;
  const ushort_t* aptr[2];
  const ushort_t* bptr;
  #pragma unroll
  for (int c = 0; c < 2; ++c) {
    int arow = m0 + w * 32 + c * 16 + sub;
    aptr[c] = Ab + (size_t)(arow >> 10) * BS + (size_t)(arow & 1023) * P + kc8;
  }
  {
    int brow = n0 + w * 16 + sub;
    bptr = Bb + (size_t)brow * K + kc8;
  }

  const int lm = l & 15, q = l >> 4;
  floatx4 acc[2][4];
  #pragma unroll
  for (int i = 0; i < 2; ++i)
    #pragma unroll
    for (int j = 0; j < 4; ++j)
      acc[i][j] = (floatx4){0.f, 0.f, 0.f, 0.f};

  const int kIters = K >> 5;
  for (int kt = 0; kt < kIters; ++kt) {
    __syncthreads();
    async16(&As[w * 1024 +   0], aptr[0]);
    async16(&As[w * 1024 + 512], aptr[1]);
    async16(&Bs[w * 512], bptr);
    aptr[0] += 32; aptr[1] += 32; bptr += 32;
    __syncthreads();
    short8 af[2], bf[4];
    #pragma unroll
    for (int i = 0; i < 2; ++i)
      af[i] = *(const short8*)&As[(w * 32 + i * 16 + lm) * 32 + q * 8];
    #pragma unroll
    for (int j = 0; j < 4; ++j)
      bf[j] = *(const short8*)&Bs[(j * 16 + lm) * 32 + q * 8];
    #pragma unroll
    for (int i = 0; i < 2; ++i)
      #pragma unroll
      for (int j = 0; j < 4; ++j)
        acc[i][j] = __builtin_amdgcn_mfma_f32_16x16x32_bf16(af[i], bf[j], acc[i][j], 0, 0, 0);
  }

  #pragma unroll
  for (int i = 0; i < 2; ++i) {
    #pragma unroll
    for (int j = 0; j < 4; ++j) {
      const int mbase = m0 + w * 32 + i * 16 + q * 4;
      const int n = n0 + j * 16 + lm;
      #pragma unroll
      for (int r = 0; r < 4; ++r) {
        const int m = mbase + r;
        float v = acc[i][j][r];
        if (EPI == 1) {
          outf[(size_t)m * NOUT + n] = v + bias[n];
        } else {
          outf[(size_t)m * NOUT + n] = v + bias[n] + res[(size_t)m * NOUT + n];
        }
      }
    }
  }
}

// ---------------------------------------------------------------------------
// QKV projection via MFMA. grid (128, 3): blockIdx.x = 64-token tile,
// blockIdx.y = matrix (0=Q,1=K,2=V). W (64x64) staged to LDS in fragment
// order; A-fragments read from global fp32, converted in-register.
// ---------------------------------------------------------------------------
__global__ __launch_bounds__(256) void qkv_mfma(
    const float* __restrict__ x,
    const float* __restrict__ Wq, const float* __restrict__ Wk, const float* __restrict__ Wv,
    ushort_t* __restrict__ qo, ushort_t* __restrict__ ko, ushort_t* __restrict__ vo)
{
  __shared__ ushort_t Ws[8 * 512];   // frag (nt,s): [((nt*2+s)*64 + lane)*8 + j]
  const int mat = blockIdx.y;
  const float* __restrict__ W = (mat == 0) ? Wq : (mat == 1) ? Wk : Wv;
  const int t = threadIdx.x;

  for (int e = t; e < 4096; e += 256) {
    const int oc = e >> 6, ic = e & 63;
    const int nt = oc >> 4, lmm = oc & 15, s = ic >> 5, qd = (ic >> 3) & 3, j = ic & 7;
    Ws[(((nt * 2 + s) * 4 + qd) * 16 + lmm) * 8 + j] = f2bf(W[e]);
  }

  const int w = t >> 6, l = t & 63;
  const int lm = l & 15, quad = l >> 4;
  const int tok0 = blockIdx.x * 64 + w * 16;

  short8 af[16];
  {
    const float* xrow = x + (size_t)(tok0 + lm) * CH + quad * 8;
    #pragma unroll
    for (int h = 0; h < 8; ++h) {
      #pragma unroll
      for (int s = 0; s < 2; ++s) {
        const float4 a = *(const float4*)(xrow + h * 64 + s * 32);
        const float4 b = *(const float4*)(xrow + h * 64 + s * 32 + 4);
        short8 f;
        f[0] = (short)f2bf(a.x); f[1] = (short)f2bf(a.y);
        f[2] = (short)f2bf(a.z); f[3] = (short)f2bf(a.w);
        f[4] = (short)f2bf(b.x); f[5] = (short)f2bf(b.y);
        f[6] = (short)f2bf(b.z); f[7] = (short)f2bf(b.w);
        af[h * 2 + s] = f;
      }
    }
  }
  __syncthreads();

  short8 bfr[8];
  #pragma unroll
  for (int nt = 0; nt < 4; ++nt)
    #pragma unroll
    for (int s = 0; s < 2; ++s)
      bfr[nt * 2 + s] = *(const short8*)&Ws[((nt * 2 + s) * 64 + l) * 8];

  const int n = tok0 >> 10, lpos = tok0 & 1023;
  ushort_t* outp;
  size_t base;
  if (mat == 0) { base = ((size_t)n * LQ + lpos) * CH; outp = qo; }
  else          { base = ((size_t)n * LP + lpos) * CH; outp = (mat == 1) ? ko : vo; }

  #pragma unroll
  for (int h = 0; h < 8; ++h) {
    floatx4 acc[4];
    #pragma unroll
    for (int nt = 0; nt < 4; ++nt) acc[nt] = (floatx4){0.f, 0.f, 0.f, 0.f};
    #pragma unroll
    for (int nt = 0; nt < 4; ++nt)
      #pragma unroll
      for (int s = 0; s < 2; ++s)
        acc[nt] = __builtin_amdgcn_mfma_f32_16x16x32_bf16(
            af[h * 2 + s], bfr[nt * 2 + s], acc[nt], 0, 0, 0);
    #pragma unroll
    for (int nt = 0; nt < 4; ++nt)
      #pragma unroll
      for (int r = 0; r < 4; ++r)
        outp[base + (size_t)(quad * 4 + r) * CH + h * 64 + nt * 16 + lm] =
            f2bf(acc[nt][r]);
  }
}

__global__ __launch_bounds__(256) void persist_kernel(
    const float* __restrict__ pk, const float* __restrict__ pv,
    ushort_t* __restrict__ ko, ushort_t* __restrict__ vo)
{
  const int t = blockIdx.x * 256 + threadIdx.x;
  const int n = t >> 13, p = (t >> 9) & 15, c = t & 511, d = c & 63;
  const size_t o = ((size_t)n * LP + LQ + p) * CH + c;
  ko[o] = f2bf(pk[p * 64 + d]);
  vo[o] = f2bf(pv[p * 64 + d]);
}

// ---------------------------------------------------------------------------
// V transpose: Vb [n][k(1040)][512] -> VT [n][d(512)][1040]
// ---------------------------------------------------------------------------
__global__ __launch_bounds__(256) void vtrans_kernel(
    const ushort_t* __restrict__ Vb, ushort_t* __restrict__ VT)
{
  __shared__ ushort_t Ls[16 * 520];
  const int n = blockIdx.y, k0 = blockIdx.x * 16;
  const int t = threadIdx.x;
  const int r = t >> 4;
  {
    const ushort_t* src = Vb + ((size_t)(n * LP + k0 + r)) * 512 + (t & 15) * 8;
    ushort_t* dst = &Ls[r * 520 + (t & 15) * 8];
    #pragma unroll
    for (int it = 0; it < 4; ++it)
      *(short8*)(dst + it * 128) = *(const short8*)(src + it * 128);
  }
  __syncthreads();
  #pragma unroll
  for (int rep = 0; rep < 2; ++rep) {
    const int d = t + rep * 256;
    short8 v0, v1;
    #pragma unroll
    for (int j = 0; j < 8; ++j) {
      v0[j] = (short)Ls[j * 520 + d];
      v1[j] = (short)Ls[(8 + j) * 520 + d];
    }
    ushort_t* dst = VT + ((size_t)(n * 512 + d)) * LP + k0;
    *(short8*)(dst)     = v0;
    *(short8*)(dst + 8) = v1;
  }
}

// ---------------------------------------------------------------------------
// MFMA flash attention with talking heads + ALiBi. (v8, measured 146 us,
// VGPR 120, no spill.) Single-pass online softmax; post-softmax talking
// heads is linear -> accumulate UNMIXED per-head o_h online, mix with tpo
// once at the end via an LDS exchange overlaid on dead Vt/Ps.
// Strict phase discipline per pair: [W: write E | bar | R: read E,
// softmax-update, write Ps+Vt | bar | PV: read Ps+Vt].
// NOTE: "V direct from global" (no Vt tile) is register-infeasible here:
// compiler budgets ~128 arch VGPRs; vpf+kf+state exceeds it -> scratch
// spill (~177 MB traffic, 1.6x slower). V stays staged in LDS.
// ---------------------------------------------------------------------------
__global__ __launch_bounds__(256, 2) void attn_mfma(
    const ushort_t* __restrict__ Qb, const ushort_t* __restrict__ Kb,
    const ushort_t* __restrict__ VT,
    const float* __restrict__ thpre, const float* __restrict__ thpost,
    ushort_t* __restrict__ aob)
{
  // manual LDS layout so the final head-mix buffer can overlay Vt/Ps
  __shared__ __align__(16) char smem[79872];
  ushort_t* Vt  = (ushort_t*)smem;                    // [512][40] ush, 40960 B
  float*    Ps  = (float*)(smem + 40960);             // [8][16][36] fl, 18432 B
  float*    Eb0 = (float*)(smem + 59392);             // [8][16][20] fl, 10240 B
  float*    Eb1 = (float*)(smem + 69632);             // [8][16][20] fl, 10240 B
  float*    Ohn = (float*)smem;                       // [8][16][68] fl, 34816 B (overlay)

  const int n = blockIdx.y, q0 = blockIdx.x * 16;
  const int t = threadIdx.x;
  const int w = t >> 6, l = t & 63;
  const int lm = l & 15, quad = l >> 4;
  const float invs = 0.044194173824159216f;    // 1/sqrt(512)

  // Q fragments for this wave's 2 heads only
  short8 qf[4];
  {
    const ushort_t* qrow = Qb + ((size_t)(n * LQ + q0 + lm)) * 512 + (w * 2) * 64 + quad * 8;
    qf[0] = *(const short8*)(qrow);
    qf[1] = *(const short8*)(qrow + 32);
    qf[2] = *(const short8*)(qrow + 64);
    qf[3] = *(const short8*)(qrow + 96);
  }

  float tps[2][8], psl[2], tpo[2][8];
  #pragma unroll
  for (int gg = 0; gg < 2; ++gg) {
    const int g = w * 2 + gg;
    float ps = 0.f;
    #pragma unroll
    for (int h = 0; h < 8; ++h) {
      float tv = thpre[g * 8 + h] * invs;
      tps[gg][h] = tv;
      ps += tv * (1.0f / (float)(2 << h));     // slope_h = 2^-(h+1)
      tpo[gg][h] = thpost[g * 8 + h];
    }
    psl[gg] = ps;
  }

  float m_[2][4], z_[2][4];
  #pragma unroll
  for (int gg = 0; gg < 2; ++gg)
    #pragma unroll
    for (int r = 0; r < 4; ++r) { m_[gg][r] = -1e30f; z_[gg][r] = 0.f; }

  floatx4 o_[2][4];
  #pragma unroll
  for (int gg = 0; gg < 2; ++gg)
    #pragma unroll
    for (int ch = 0; ch < 4; ++ch) o_[gg][ch] = (floatx4){0.f, 0.f, 0.f, 0.f};

  // ---- global sources ----
  const ushort_t* kg  = Kb + ((size_t)(n * LP + lm)) * 512 + (w * 2) * 64 + quad * 8;
  const ushort_t* vgA = VT + ((size_t)(n * 512) + t) * LP;
  const ushort_t* vgB = VT + ((size_t)(n * 512) + t + 256) * LP;

  short8 kfE[4], kfO[4], vX[4], vY[4];

  auto loadKg = [&](short8 (&r)[4], int step) {
    const ushort_t* p = kg + (size_t)step * 8192;
    r[0] = *(const short8*)(p);
    r[1] = *(const short8*)(p + 32);
    r[2] = *(const short8*)(p + 64);
    r[3] = *(const short8*)(p + 96);
  };
  auto loadVg = [&](short8 (&r)[4], int off) {
    r[0] = *(const short8*)(vgA + off); r[1] = *(const short8*)(vgA + off + 8);
    r[2] = *(const short8*)(vgB + off); r[3] = *(const short8*)(vgB + off + 8);
  };
  auto storeV = [&](short8 (&r)[4], int sub) {
    ushort_t* d0 = &Vt[(size_t)t * 40 + sub * 16];
    ushort_t* d1 = &Vt[(size_t)(t + 256) * 40 + sub * 16];
    *(short8*)(d0)     = r[0]; *(short8*)(d0 + 8) = r[1];
    *(short8*)(d1)     = r[2]; *(short8*)(d1 + 8) = r[3];
  };

  // wave's 2-head QK^T -> E[buf][h][k=lm][q=quad*4+j]
  auto qktE = [&](short8 (&kf)[4], float* Eb) {
    #pragma unroll
    for (int hh = 0; hh < 2; ++hh) {
      floatx4 e = (floatx4){0.f, 0.f, 0.f, 0.f};
      e = __builtin_amdgcn_mfma_f32_16x16x32_bf16(qf[hh * 2 + 0], kf[hh * 2 + 0], e, 0, 0, 0);
      e = __builtin_amdgcn_mfma_f32_16x16x32_bf16(qf[hh * 2 + 1], kf[hh * 2 + 1], e, 0, 0, 0);
      *(floatx4*)&Eb[(((w * 2 + hh) * 16 + lm)) * 20 + quad * 4] = e;
    }
  };

  // online softmax update for one pair (steps 2p, 2p+1). Reads Eb0/Eb1,
  // rescales o_/z_, writes Ps (both subs).
  auto online2 = [&](int p) {
    float s0[2][4], s1[2][4];
    #pragma unroll
    for (int gg = 0; gg < 2; ++gg)
      #pragma unroll
      for (int r = 0; r < 4; ++r) { s0[gg][r] = 0.f; s1[gg][r] = 0.f; }
    #pragma unroll
    for (int h = 0; h < 8; ++h) {
      const floatx4 a = *(const floatx4*)&Eb0[(h * 16 + lm) * 20 + quad * 4];
      const floatx4 b = *(const floatx4*)&Eb1[(h * 16 + lm) * 20 + quad * 4];
      #pragma unroll
      for (int gg = 0; gg < 2; ++gg) {
        const float tv = tps[gg][h];
        #pragma unroll
        for (int r = 0; r < 4; ++r) {
          s0[gg][r] += tv * a[r];
          s1[gg][r] += tv * b[r];
        }
      }
    }
    const int k0 = 32 * p;
    float pm[2][4];
    #pragma unroll
    for (int r = 0; r < 4; ++r) {
      const float qpos = (float)(q0 + quad * 4 + r);
      const float d0 = fabsf(qpos - (float)(k0 + lm));
      const float d1 = fabsf(qpos - (float)(k0 + 16 + lm));
      #pragma unroll
      for (int gg = 0; gg < 2; ++gg) {
        s0[gg][r] -= d0 * psl[gg];
        s1[gg][r] -= d1 * psl[gg];
        pm[gg][r] = fmaxf(s0[gg][r], s1[gg][r]);
      }
    }
    #pragma unroll
    for (int off = 1; off < 16; off <<= 1)
      #pragma unroll
      for (int gg = 0; gg < 2; ++gg)
        #pragma unroll
        for (int r = 0; r < 4; ++r)
          pm[gg][r] = fmaxf(pm[gg][r], __shfl_xor(pm[gg][r], off));
    float sc[2][4];
    #pragma unroll
    for (int gg = 0; gg < 2; ++gg)
      #pragma unroll
      for (int r = 0; r < 4; ++r) {
        const float mn = fmaxf(m_[gg][r], pm[gg][r]);
        sc[gg][r] = __expf(m_[gg][r] - mn);
        const float p0 = __expf(s0[gg][r] - mn);
        const float p1 = __expf(s1[gg][r] - mn);
        z_[gg][r] = z_[gg][r] * sc[gg][r] + p0 + p1;
        m_[gg][r] = mn;
        float* prow = &Ps[((w * 2 + gg) * 16 + quad * 4 + r) * 36];
        prow[lm] = p0;
        prow[16 + lm] = p1;
      }
    #pragma unroll
    for (int gg = 0; gg < 2; ++gg)
      #pragma unroll
      for (int ch = 0; ch < 4; ++ch)
        #pragma unroll
        for (int r = 0; r < 4; ++r)
          o_[gg][ch][r] *= sc[gg][r];
  };

  // tail: single step 64 (persistent keys, no alibi)
  auto online1 = [&]() {
    float s0[2][4];
    #pragma unroll
    for (int gg = 0; gg < 2; ++gg)
      #pragma unroll
      for (int r = 0; r < 4; ++r) s0[gg][r] = 0.f;
    #pragma unroll
    for (int h = 0; h < 8; ++h) {
      const floatx4 a = *(const floatx4*)&Eb0[(h * 16 + lm) * 20 + quad * 4];
      #pragma unroll
      for (int gg = 0; gg < 2; ++gg) {
        const float tv = tps[gg][h];
        #pragma unroll
        for (int r = 0; r < 4; ++r) s0[gg][r] += tv * a[r];
      }
    }
    float pm[2][4];
    #pragma unroll
    for (int gg = 0; gg < 2; ++gg)
      #pragma unroll
      for (int r = 0; r < 4; ++r) pm[gg][r] = s0[gg][r];
    #pragma unroll
    for (int off = 1; off < 16; off <<= 1)
      #pragma unroll
      for (int gg = 0; gg < 2; ++gg)
        #pragma unroll
        for (int r = 0; r < 4; ++r)
          pm[gg][r] = fmaxf(pm[gg][r], __shfl_xor(pm[gg][r], off));
    float sc[2][4];
    #pragma unroll
    for (int gg = 0; gg < 2; ++gg)
      #pragma unroll
      for (int r = 0; r < 4; ++r) {
        const float mn = fmaxf(m_[gg][r], pm[gg][r]);
        sc[gg][r] = __expf(m_[gg][r] - mn);
        const float p0 = __expf(s0[gg][r] - mn);
        z_[gg][r] = z_[gg][r] * sc[gg][r] + p0;
        m_[gg][r] = mn;
        float* prow = &Ps[((w * 2 + gg) * 16 + quad * 4 + r) * 36];
        prow[lm] = p0;
        prow[16 + lm] = 0.f;
      }
    #pragma unroll
    for (int gg = 0; gg < 2; ++gg)
      #pragma unroll
      for (int ch = 0; ch < 4; ++ch)
        #pragma unroll
        for (int r = 0; r < 4; ++r)
          o_[gg][ch][r] *= sc[gg][r];
  };

  // P·V for own 2 heads: A-frag from Ps rows of head w*2+gg, B from Vt
  auto pv = [&]() {
    #pragma unroll
    for (int gg = 0; gg < 2; ++gg) {
      const float4 pa = *(const float4*)&Ps[((w * 2 + gg) * 16 + lm) * 36 + quad * 8];
      const float4 pb = *(const float4*)&Ps[((w * 2 + gg) * 16 + lm) * 36 + quad * 8 + 4];
      short8 pk;
      pk[0] = (short)f2bf(pa.x); pk[1] = (short)f2bf(pa.y);
      pk[2] = (short)f2bf(pa.z); pk[3] = (short)f2bf(pa.w);
      pk[4] = (short)f2bf(pb.x); pk[5] = (short)f2bf(pb.y);
      pk[6] = (short)f2bf(pb.z); pk[7] = (short)f2bf(pb.w);
      #pragma unroll
      for (int ch = 0; ch < 4; ++ch) {
        const int d = (w * 2 + gg) * 64 + ch * 16 + lm;
        const short8 vf = *(const short8*)&Vt[d * 40 + quad * 8];
        o_[gg][ch] = __builtin_amdgcn_mfma_f32_16x16x32_bf16(pk, vf, o_[gg][ch], 0, 0, 0);
      }
    }
  };

  // ---------------- single pass ------------------------------------------
  loadKg(kfE, 0);
  loadKg(kfO, 1);
  loadVg(vX, 0);
  loadVg(vY, 16);

  for (int p = 0; p < 32; ++p) {
    // W: write E (both bufs); prefetch next K pair
    qktE(kfE, Eb0);
    qktE(kfO, Eb1);
    loadKg(kfE, 2 * p + 2);               // p=31 -> step 64 (tail)
    if (p < 31) loadKg(kfO, 2 * p + 3);
    __syncthreads();                      // E ready; prev pv() done
    // R: read E, online update, write Ps + Vt; prefetch next V pair
    online2(p);
    storeV(vX, 0);
    storeV(vY, 1);
    loadVg(vX, 32 * (p + 1));             // p=31 -> offset 1024 (tail)
    if (p < 31) loadVg(vY, 32 * (p + 1) + 16);
    __syncthreads();                      // Ps/Vt ready; E readers done
    // PV: read Ps (own heads) + Vt, accumulate into o_
    pv();
  }
  // tail: step 64 (kfE holds it; vX holds V offset 1024)
  qktE(kfE, Eb0);
  __syncthreads();                        // E ready; pv(pair 31) done
  online1();
  storeV(vX, 0);
  __syncthreads();
  pv();                                   // sub1 P == 0 -> no contribution

  // ---------------- epilogue: z combine, per-head normalize, head mix ----
  #pragma unroll
  for (int off = 1; off < 16; off <<= 1)
    #pragma unroll
    for (int gg = 0; gg < 2; ++gg)
      #pragma unroll
      for (int r = 0; r < 4; ++r)
        z_[gg][r] += __shfl_xor(z_[gg][r], off);
  #pragma unroll
  for (int gg = 0; gg < 2; ++gg)
    #pragma unroll
    for (int r = 0; r < 4; ++r) {
      const float zi = 1.0f / z_[gg][r];
      #pragma unroll
      for (int ch = 0; ch < 4; ++ch) o_[gg][ch][r] *= zi;
    }

  __syncthreads();    // all pv() LDS reads done; safe to overlay Ohn
  #pragma unroll
  for (int gg = 0; gg < 2; ++gg)
    #pragma unroll
    for (int ch = 0; ch < 4; ++ch)
      #pragma unroll
      for (int r = 0; r < 4; ++r)
        Ohn[(w * 2 + gg) * 1088 + (quad * 4 + r) * 68 + ch * 16 + lm] = o_[gg][ch][r];
  __syncthreads();

  float acc[2][4][4];
  #pragma unroll
  for (int gg = 0; gg < 2; ++gg)
    #pragma unroll
    for (int ch = 0; ch < 4; ++ch)
      #pragma unroll
      for (int r = 0; r < 4; ++r) acc[gg][ch][r] = 0.f;
  #pragma unroll
  for (int h = 0; h < 8; ++h) {
    #pragma unroll
    for (int ch = 0; ch < 4; ++ch)
      #pragma unroll
      for (int r = 0; r < 4; ++r) {
        const float ov = Ohn[h * 1088 + (quad * 4 + r) * 68 + ch * 16 + lm];
        acc[0][ch][r] += tpo[0][h] * ov;
        acc[1][ch][r] += tpo[1][h] * ov;
      }
  }

  #pragma unroll
  for (int gg = 0; gg < 2; ++gg)
    #pragma unroll
    for (int ch = 0; ch < 4; ++ch) {
      const int d = (w * 2 + gg) * 64 + ch * 16 + lm;
      #pragma unroll
      for (int r = 0; r < 4; ++r)
        aob[((size_t)(n * LQ + q0 + quad * 4 + r)) * 512 + d] = f2bf(acc[gg][ch][r]);
    }
}

// ---------------------------------------------------------------------------
// swiglu: h = silu(h1+b1)*(h2+b2), raw [8192][4096] bf16 -> padded bf16
// vectorized: one short8 per thread (2048 cols / 256 threads = 8)
// ---------------------------------------------------------------------------
__global__ __launch_bounds__(256) void swiglu_kernel(
    const ushort_t* __restrict__ hraw, const float* __restrict__ bias,
    ushort_t* __restrict__ hpad)
{
  const int tok = blockIdx.x;
  const int n = tok >> 10, l = tok & 1023;
  const int c = threadIdx.x * 8;
  const size_t src = (size_t)tok * 4096 + c;
  const size_t dst = ((size_t)n * 1026 + l + 1) * 2048 + c;
  const short8 h1v = *(const short8*)&hraw[src];
  const short8 h2v = *(const short8*)&hraw[src + 2048];
  const float4 b1a = *(const float4*)&bias[c];
  const float4 b1b = *(const float4*)&bias[c + 4];
  const float4 b2a = *(const float4*)&bias[2048 + c];
  const float4 b2b = *(const float4*)&bias[2048 + c + 4];
  const float bb1[8] = {b1a.x, b1a.y, b1a.z, b1a.w, b1b.x, b1b.y, b1b.z, b1b.w};
  const float bb2[8] = {b2a.x, b2a.y, b2a.z, b2a.w, b2b.x, b2b.y, b2b.z, b2b.w};
  short8 o;
  #pragma unroll
  for (int j = 0; j < 8; ++j) {
    const float h1 = bf2f((ushort_t)h1v[j]) + bb1[j];
    const float h2 = bf2f((ushort_t)h2v[j]) + bb2[j];
    const float s = h1 / (1.f + __expf(-h1));
    o[j] = (short)f2bf(s * h2);
  }
  *(short8*)&hpad[dst] = o;
}

__global__ __launch_bounds__(256) void zero_pads_kernel(
    ushort_t* __restrict__ x1b, ushort_t* __restrict__ hpad)
{
  const int b = blockIdx.x;
  const int n = b >> 1, side = b & 1;
  const size_t r = (size_t)n * 1026 + side * 1025;
  ushort2 z; z.x = 0; z.y = 0;
  *(ushort2*)&x1b[r * 512 + threadIdx.x * 2] = z;
  #pragma unroll
  for (int i = 0; i < 4; ++i)
    *(ushort2*)&hpad[r * 2048 + (threadIdx.x + 256 * i) * 2] = z;
}

// ---------------------------------------------------------------------------
// LayerNorm (fp32) + optional bf16 padded copy
// ---------------------------------------------------------------------------
__global__ __launch_bounds__(256) void ln_kernel(
    const float* __restrict__ in, const float* __restrict__ res,
    const float* __restrict__ g, const float* __restrict__ b,
    float* __restrict__ outp, ushort_t* __restrict__ bfout)
{
  const int w = threadIdx.x >> 6, lane = threadIdx.x & 63;
  const int tok = blockIdx.x * 4 + w;
  const size_t base = (size_t)tok * CH;
  float4 v0 = *(const float4*)&in[base + (lane << 2)];
  float4 v1 = *(const float4*)&in[base + 256 + (lane << 2)];
  if (res != nullptr) {
    float4 r0 = *(const float4*)&res[base + (lane << 2)];
    float4 r1 = *(const float4*)&res[base + 256 + (lane << 2)];
    v0.x += r0.x; v0.y += r0.y; v0.z += r0.z; v0.w += r0.w;
    v1.x += r1.x; v1.y += r1.y; v1.z += r1.z; v1.w += r1.w;
  }
  float s = v0.x + v0.y + v0.z + v0.w + v1.x + v1.y + v1.z + v1.w;
  #pragma unroll
  for (int off = 32; off > 0; off >>= 1) s += __shfl_xor(s, off);
  const float mu = s * (1.f / 512.f);
  float d0 = v0.x - mu, d1 = v0.y - mu, d2 = v0.z - mu, d3 = v0.w - mu;
  float d4 = v1.x - mu, d5 = v1.y - mu, d6 = v1.z - mu, d7 = v1.w - mu;
  float vs = d0*d0 + d1*d1 + d2*d2 + d3*d3 + d4*d4 + d5*d5 + d6*d6 + d7*d7;
  #pragma unroll
  for (int off = 32; off > 0; off >>= 1) vs += __shfl_xor(vs, off);
  const float r = rsqrtf(vs * (1.f / 512.f) + 1e-5f);
  float4 ga = *(const float4*)&g[(lane << 2)];
  float4 gb = *(const float4*)&g[256 + (lane << 2)];
  float4 ba = *(const float4*)&b[(lane << 2)];
  float4 bb = *(const float4*)&b[256 + (lane << 2)];
  float4 o0, o1;
  o0.x = d0 * r * ga.x + ba.x; o0.y = d1 * r * ga.y + ba.y;
  o0.z = d2 * r * ga.z + ba.z; o0.w = d3 * r * ga.w + ba.w;
  o1.x = d4 * r * gb.x + bb.x; o1.y = d5 * r * gb.y + bb.y;
  o1.z = d6 * r * gb.z + bb.z; o1.w = d7 * r * gb.w + bb.w;
  *(float4*)&outp[base + (lane << 2)] = o0;
  *(float4*)&outp[base + 256 + (lane << 2)] = o1;
  if (bfout != nullptr) {
    const int n = tok >> 10, ll = tok & 1023;
    const size_t bb2 = ((size_t)n * 1026 + ll + 1) * 512;
    ushort4 u0 = make_ushort4(f2bf(o0.x), f2bf(o0.y), f2bf(o0.z), f2bf(o0.w));
    ushort4 u1 = make_ushort4(f2bf(o1.x), f2bf(o1.y), f2bf(o1.z), f2bf(o1.w));
    *(ushort4*)&bfout[bb2 + (lane << 2)] = u0;
    *(ushort4*)&bfout[bb2 + 256 + (lane << 2)] = u1;
  }
}

// ---------------------------------------------------------------------------
extern "C" void kernel_launch(void* const* d_in, const int* in_sizes, int n_in,
                              void* d_out, int out_size, void* d_ws, size_t ws_size,
                              hipStream_t stream)
{
  (void)in_sizes; (void)n_in; (void)out_size; (void)ws_size;
  const float* x      = (const float*)d_in[0];
  const float* Wq     = (const float*)d_in[1];
  const float* Wk     = (const float*)d_in[2];
  const float* Wv     = (const float*)d_in[3];
  const float* Wo     = (const float*)d_in[4];
  const float* bo     = (const float*)d_in[5];
  const float* th_pre = (const float*)d_in[6];
  const float* th_post= (const float*)d_in[7];
  const float* p_keys = (const float*)d_in[8];
  const float* p_vals = (const float*)d_in[9];
  const float* c1w    = (const float*)d_in[10];
  const float* c1b    = (const float*)d_in[11];
  const float* c2w    = (const float*)d_in[12];
  const float* c2b    = (const float*)d_in[13];
  const float* ln1g   = (const float*)d_in[14];
  const float* ln1b   = (const float*)d_in[15];
  const float* ln2g   = (const float*)d_in[16];
  const float* ln2b   = (const float*)d_in[17];

  float* ws  = (float*)d_ws;
  float* out = (float*)d_out;

  ushort_t* Qb   = (ushort_t*)(ws + O_QB);
  ushort_t* Kb   = (ushort_t*)(ws + O_KB);
  ushort_t* Vb   = (ushort_t*)(ws + O_VB);
  ushort_t* VT   = (ushort_t*)(ws + O_VT);
  ushort_t* aob  = (ushort_t*)(ws + O_AOB);
  float*    abf  = ws + O_AF;
  float*    fbf  = abf;
  ushort_t* x1b  = (ushort_t*)(ws + O_X1B);
  ushort_t* hpad = (ushort_t*)(ws + O_HPAD);
  ushort_t* hraw = (ushort_t*)ws;         // overlays dead attn buffers
  ushort_t* w1p  = (ushort_t*)(ws + O_W1);
  ushort_t* w2p  = (ushort_t*)(ws + O_W2);
  ushort_t* wop  = (ushort_t*)(ws + O_WO);

  pack_bf16_kernel<<<4096, 256, 0, stream>>>(c1w, w1p, 1536, 3, 9);
  pack_bf16_kernel<<<512,  256, 0, stream>>>(c2w, w2p, 6144, 3, 11);
  pack_bf16_kernel<<<512,  256, 0, stream>>>(Wo,  wop, 512,  1, 9);

  qkv_mfma<<<dim3(128, 3), 256, 0, stream>>>(x, Wq, Wk, Wv, Qb, Kb, Vb);
  persist_kernel<<<256, 256, 0, stream>>>(p_keys, p_vals, Kb, Vb);
  vtrans_kernel<<<dim3(65, 8), 256, 0, stream>>>(Vb, VT);

  attn_mfma<<<dim3(64, 8), 256, 0, stream>>>(Qb, Kb, VT, th_pre, th_post, aob);

  // Wo: M=8192 N=512 K=512, +bias +residual(x) -> abf fp32 (128x64 tiles)
  mfma_gemm_n64<2><<<dim3(64, 8), 256, 0, stream>>>(
      aob, wop, 512, 1024 * 512, 512, 512, bo, x, abf);

  ln_kernel<<<2048, 256, 0, stream>>>(abf, nullptr, ln1g, ln1b, out, x1b);
  zero_pads_kernel<<<16, 256, 0, stream>>>(x1b, hpad);

  // conv1: M=8192 N=4096 K=1536 -> hraw bf16 (128x128 tiles, compute-bound)
  mfma_gemm<0><<<dim3(64, 32), 256, 0, stream>>>(
      x1b, w1p, 1536, 1026 * 512, 512, 4096, nullptr, nullptr, nullptr, hraw);

  swiglu_kernel<<<8192, 256, 0, stream>>>(hraw, c1b, hpad);

  // conv2: M=8192 N=512 K=6144, +bias -> fbf fp32 (128x64 tiles, no split-K)
  mfma_gemm_n64<1><<<dim3(64, 8), 256, 0, stream>>>(
      hpad, w2p, 6144, 1026 * 2048, 2048, 512, c2b, nullptr, fbf);

  ln_kernel<<<2048, 256, 0, stream>>>(fbf, out, ln2g, ln2b, out, nullptr);
}

// Round 9
// 526.317 us; speedup vs baseline: 1.0389x; 1.0389x over previous
//
#include <hip/hip_runtime.h>
#include <cstddef>
#include <cstdint>

#define NB   8
#define LQ   1024
#define CH   512
#define HHE  8
#define HDD  64
#define PPM  16
#define LP   1040     // L + P
#define HID  2048

typedef unsigned short ushort_t;
typedef __attribute__((ext_vector_type(8))) short short8;
typedef __attribute__((ext_vector_type(4))) float floatx4;

// ---- workspace layout (float element offsets) ----
static const size_t O_QB   = 0;          // Qb bf16   (2,097,152 fl)
static const size_t O_KB   = 2097152;    // Kb bf16   (2,129,920 fl)
static const size_t O_VB   = 4227072;    // Vb bf16   (2,129,920 fl)
static const size_t O_VT   = 6356992;    // VT bf16   (2,129,920 fl)
static const size_t O_AOB  = 8486912;    // aob bf16  (2,097,152 fl)
static const size_t O_AF   = 10584064;   // abf fp32 (4,194,304 fl)
// hraw bf16 overlays floats [0 .. 16,777,216) -- all of the above are dead then
// conv2 partials fp32 [4][4,194,304] also overlay [0 .. 16,777,216)
static const size_t O_X1B  = 16777216;   // x1b padded bf16 (2,101,248 fl)
static const size_t O_HPAD = 18878464;   // hpad bf16 (8,404,992 fl)
static const size_t O_W1   = 27283456;   // w1 bf16   (3,145,728 fl)
static const size_t O_W2   = 30429184;   // w2 bf16   (1,572,864 fl)
static const size_t O_WO   = 32002048;   // wo bf16   (131,072 fl)
// total 32,133,120 floats = 128.5 MB

__device__ __forceinline__ ushort_t f2bf(float f) {
  uint32_t u = __float_as_uint(f);
  u += 0x7FFFu + ((u >> 16) & 1u);
  return (ushort_t)(u >> 16);
}
__device__ __forceinline__ float bf2f(ushort_t h) {
  return __uint_as_float(((uint32_t)h) << 16);
}

__device__ __forceinline__ void async16(ushort_t* lds, const ushort_t* g) {
  __builtin_amdgcn_global_load_lds(
      (const __attribute__((address_space(1))) void*)g,
      (__attribute__((address_space(3))) void*)lds, 16, 0, 0);
}

// ---------------------------------------------------------------------------
// weight pack to bf16 [oc][k], k = dl*IC + ic; src[oc*K + ic*KD + dl]
// ---------------------------------------------------------------------------
__global__ __launch_bounds__(256) void pack_bf16_kernel(
    const float* __restrict__ src, ushort_t* __restrict__ dst,
    int K, int KD, int icShift)
{
  const int oc = blockIdx.x;
  const int icMask = (1 << icShift) - 1;
  for (int k = threadIdx.x; k < K; k += 256) {
    int ic = k & icMask, dl = k >> icShift;
    dst[(size_t)oc * K + k] = f2bf(src[(size_t)oc * K + ic * KD + dl]);
  }
}

// ---------------------------------------------------------------------------
// Generic bf16 MFMA GEMM, 128x128 tile, BK=32, global_load_lds staging.
// blockIdx.z = K-split slice (EPI==3 writes raw partials to
// outf + z*4194304). v9 lesson: thinner (128x64) tiles REGRESS on K-long
// shapes -- per-step MFMA/staging ratio halves and the per-step vmcnt(0)
// drain dominates. Keep 128x128 + split-K for latency-bound shapes.
// ---------------------------------------------------------------------------
template<int EPI>
__global__ __launch_bounds__(256, 2) void mfma_gemm(
    const ushort_t* __restrict__ Ab, const ushort_t* __restrict__ Bb,
    int K, int BS, int P, int NOUT,
    const float* __restrict__ bias, const float* __restrict__ res,
    float* __restrict__ outf, ushort_t* __restrict__ outh)
{
  __shared__ ushort_t As[128 * 32];
  __shared__ ushort_t Bs[128 * 32];
  const int t = threadIdx.x;
  const int w = t >> 6, l = t & 63;
  const int m0 = blockIdx.x * 128, n0 = blockIdx.y * 128;

  const int kChunk = K / (int)gridDim.z;
  const int kstart = blockIdx.z * kChunk;

  const int sub = l >> 2;
  const int kc8 = (l & 3) * 8;
  const ushort_t* aptr[2];
  const ushort_t* bptr[2];
  #pragma unroll
  for (int c = 0; c < 2; ++c) {
    int arow = m0 + w * 32 + c * 16 + sub;
    aptr[c] = Ab + (size_t)(arow >> 10) * BS + (size_t)(arow & 1023) * P + kc8 + kstart;
    int brow = n0 + w * 32 + c * 16 + sub;
    bptr[c] = Bb + (size_t)brow * K + kc8 + kstart;
  }

  const int wm = w >> 1, wn = w & 1;
  const int lm = l & 15, q = l >> 4;
  floatx4 acc[4][4];
  #pragma unroll
  for (int i = 0; i < 4; ++i)
    #pragma unroll
    for (int j = 0; j < 4; ++j)
      acc[i][j] = (floatx4){0.f, 0.f, 0.f, 0.f};

  const int kIters = kChunk >> 5;
  for (int kt = 0; kt < kIters; ++kt) {
    __syncthreads();
    async16(&As[w * 1024 +   0], aptr[0]);
    async16(&As[w * 1024 + 512], aptr[1]);
    async16(&Bs[w * 1024 +   0], bptr[0]);
    async16(&Bs[w * 1024 + 512], bptr[1]);
    aptr[0] += 32; aptr[1] += 32; bptr[0] += 32; bptr[1] += 32;
    __syncthreads();
    short8 af[4], bf[4];
    #pragma unroll
    for (int i = 0; i < 4; ++i)
      af[i] = *(const short8*)&As[(wm * 64 + i * 16 + lm) * 32 + q * 8];
    #pragma unroll
    for (int i = 0; i < 4; ++i)
      bf[i] = *(const short8*)&Bs[(wn * 64 + i * 16 + lm) * 32 + q * 8];
    #pragma unroll
    for (int i = 0; i < 4; ++i)
      #pragma unroll
      for (int j = 0; j < 4; ++j)
        acc[i][j] = __builtin_amdgcn_mfma_f32_16x16x32_bf16(af[i], bf[j], acc[i][j], 0, 0, 0);
  }

  #pragma unroll
  for (int i = 0; i < 4; ++i) {
    #pragma unroll
    for (int j = 0; j < 4; ++j) {
      const int mbase = m0 + wm * 64 + i * 16 + q * 4;
      const int n = n0 + wn * 64 + j * 16 + lm;
      #pragma unroll
      for (int r = 0; r < 4; ++r) {
        const int m = mbase + r;
        float v = acc[i][j][r];
        if (EPI == 0) {
          outh[(size_t)m * NOUT + n] = f2bf(v);
        } else if (EPI == 1) {
          outf[(size_t)m * NOUT + n] = v + bias[n];
        } else if (EPI == 2) {
          outf[(size_t)m * NOUT + n] = v + bias[n] + res[(size_t)m * NOUT + n];
        } else {
          outf[(size_t)blockIdx.z * 4194304 + (size_t)m * NOUT + n] = v;
        }
      }
    }
  }
}

// ---------------------------------------------------------------------------
// sum 4 K-split partials + bias, in place into partial slice 0
// ---------------------------------------------------------------------------
__global__ __launch_bounds__(256) void ksum_kernel(
    float* __restrict__ pb, const float* __restrict__ bias)
{
  const size_t i = ((size_t)blockIdx.x * 256 + threadIdx.x) * 4;
  float4 a = *(const float4*)&pb[i];
  float4 b = *(const float4*)&pb[i +  4194304];
  float4 c = *(const float4*)&pb[i +  8388608];
  float4 d = *(const float4*)&pb[i + 12582912];
  const int col = (int)(i & 511);
  float4 bi = *(const float4*)&bias[col];
  float4 o;
  o.x = a.x + b.x + c.x + d.x + bi.x;
  o.y = a.y + b.y + c.y + d.y + bi.y;
  o.z = a.z + b.z + c.z + d.z + bi.z;
  o.w = a.w + b.w + c.w + d.w + bi.w;
  *(float4*)&pb[i] = o;
}

// ---------------------------------------------------------------------------
// QKV projection via MFMA. grid (128, 3): blockIdx.x = 64-token tile,
// blockIdx.y = matrix (0=Q,1=K,2=V). W (64x64) staged to LDS in fragment
// order; A-fragments read from global fp32, converted in-register.
// ---------------------------------------------------------------------------
__global__ __launch_bounds__(256) void qkv_mfma(
    const float* __restrict__ x,
    const float* __restrict__ Wq, const float* __restrict__ Wk, const float* __restrict__ Wv,
    ushort_t* __restrict__ qo, ushort_t* __restrict__ ko, ushort_t* __restrict__ vo)
{
  __shared__ ushort_t Ws[8 * 512];   // frag (nt,s): [((nt*2+s)*64 + lane)*8 + j]
  const int mat = blockIdx.y;
  const float* __restrict__ W = (mat == 0) ? Wq : (mat == 1) ? Wk : Wv;
  const int t = threadIdx.x;

  for (int e = t; e < 4096; e += 256) {
    const int oc = e >> 6, ic = e & 63;
    const int nt = oc >> 4, lmm = oc & 15, s = ic >> 5, qd = (ic >> 3) & 3, j = ic & 7;
    Ws[(((nt * 2 + s) * 4 + qd) * 16 + lmm) * 8 + j] = f2bf(W[e]);
  }

  const int w = t >> 6, l = t & 63;
  const int lm = l & 15, quad = l >> 4;
  const int tok0 = blockIdx.x * 64 + w * 16;

  short8 af[16];
  {
    const float* xrow = x + (size_t)(tok0 + lm) * CH + quad * 8;
    #pragma unroll
    for (int h = 0; h < 8; ++h) {
      #pragma unroll
      for (int s = 0; s < 2; ++s) {
        const float4 a = *(const float4*)(xrow + h * 64 + s * 32);
        const float4 b = *(const float4*)(xrow + h * 64 + s * 32 + 4);
        short8 f;
        f[0] = (short)f2bf(a.x); f[1] = (short)f2bf(a.y);
        f[2] = (short)f2bf(a.z); f[3] = (short)f2bf(a.w);
        f[4] = (short)f2bf(b.x); f[5] = (short)f2bf(b.y);
        f[6] = (short)f2bf(b.z); f[7] = (short)f2bf(b.w);
        af[h * 2 + s] = f;
      }
    }
  }
  __syncthreads();

  short8 bfr[8];
  #pragma unroll
  for (int nt = 0; nt < 4; ++nt)
    #pragma unroll
    for (int s = 0; s < 2; ++s)
      bfr[nt * 2 + s] = *(const short8*)&Ws[((nt * 2 + s) * 64 + l) * 8];

  const int n = tok0 >> 10, lpos = tok0 & 1023;
  ushort_t* outp;
  size_t base;
  if (mat == 0) { base = ((size_t)n * LQ + lpos) * CH; outp = qo; }
  else          { base = ((size_t)n * LP + lpos) * CH; outp = (mat == 1) ? ko : vo; }

  #pragma unroll
  for (int h = 0; h < 8; ++h) {
    floatx4 acc[4];
    #pragma unroll
    for (int nt = 0; nt < 4; ++nt) acc[nt] = (floatx4){0.f, 0.f, 0.f, 0.f};
    #pragma unroll
    for (int nt = 0; nt < 4; ++nt)
      #pragma unroll
      for (int s = 0; s < 2; ++s)
        acc[nt] = __builtin_amdgcn_mfma_f32_16x16x32_bf16(
            af[h * 2 + s], bfr[nt * 2 + s], acc[nt], 0, 0, 0);
    #pragma unroll
    for (int nt = 0; nt < 4; ++nt)
      #pragma unroll
      for (int r = 0; r < 4; ++r)
        outp[base + (size_t)(quad * 4 + r) * CH + h * 64 + nt * 16 + lm] =
            f2bf(acc[nt][r]);
  }
}

__global__ __launch_bounds__(256) void persist_kernel(
    const float* __restrict__ pk, const float* __restrict__ pv,
    ushort_t* __restrict__ ko, ushort_t* __restrict__ vo)
{
  const int t = blockIdx.x * 256 + threadIdx.x;
  const int n = t >> 13, p = (t >> 9) & 15, c = t & 511, d = c & 63;
  const size_t o = ((size_t)n * LP + LQ + p) * CH + c;
  ko[o] = f2bf(pk[p * 64 + d]);
  vo[o] = f2bf(pv[p * 64 + d]);
}

// ---------------------------------------------------------------------------
// V transpose: Vb [n][k(1040)][512] -> VT [n][d(512)][1040]
// ---------------------------------------------------------------------------
__global__ __launch_bounds__(256) void vtrans_kernel(
    const ushort_t* __restrict__ Vb, ushort_t* __restrict__ VT)
{
  __shared__ ushort_t Ls[16 * 520];
  const int n = blockIdx.y, k0 = blockIdx.x * 16;
  const int t = threadIdx.x;
  const int r = t >> 4;
  {
    const ushort_t* src = Vb + ((size_t)(n * LP + k0 + r)) * 512 + (t & 15) * 8;
    ushort_t* dst = &Ls[r * 520 + (t & 15) * 8];
    #pragma unroll
    for (int it = 0; it < 4; ++it)
      *(short8*)(dst + it * 128) = *(const short8*)(src + it * 128);
  }
  __syncthreads();
  #pragma unroll
  for (int rep = 0; rep < 2; ++rep) {
    const int d = t + rep * 256;
    short8 v0, v1;
    #pragma unroll
    for (int j = 0; j < 8; ++j) {
      v0[j] = (short)Ls[j * 520 + d];
      v1[j] = (short)Ls[(8 + j) * 520 + d];
    }
    ushort_t* dst = VT + ((size_t)(n * 512 + d)) * LP + k0;
    *(short8*)(dst)     = v0;
    *(short8*)(dst + 8) = v1;
  }
}

// ---------------------------------------------------------------------------
// MFMA flash attention with talking heads + ALiBi.  v10:
// ONE barrier per 32-key pair (was 2). Dataflow facts that make it safe:
//  - Ps and Vt are WAVE-PRIVATE (wave w only touches its heads 2w,2w+1;
//    Vt staging rows remapped so each wave stages the rows it consumes).
//    Their write-after-read hazards are same-wave program order.
//  - only the E exchange is cross-wave; E rotates over FOUR bf16 buffers
//    (2 steps x 2 pairs), so every cross-wave write->read / read->write
//    pair is separated by exactly one barrier.
// Phase p: { pv(p-1); qktE(p+1)->E[(2p+2..3)&3] [setprio]; online2(p)
//   reads E[(2p..2p+1)&3]; storeV(p); prefetch K(p+2),V(p+1) } barrier.
// Numerics: E stored bf16 (|e|~0.2, quantization ~4e-4 -> delta-s ~2e-5,
// negligible); Ps bf16 is BIT-IDENTICAL (same f2bf moved from pv to
// online2). Register budget unchanged from v8 (VGPR 120, no spill).
// ---------------------------------------------------------------------------
__global__ __launch_bounds__(256, 2) void attn_mfma(
    const ushort_t* __restrict__ Qb, const ushort_t* __restrict__ Kb,
    const ushort_t* __restrict__ VT,
    const float* __restrict__ thpre, const float* __restrict__ thpost,
    ushort_t* __restrict__ aob)
{
  // Vt [512][40]us 40960B | Psb [8][16][40]us 10240B | Eb 4x[8][16][20]us 20480B
  __shared__ __align__(16) char smem[71680];
  ushort_t* Vt  = (ushort_t*)smem;
  ushort_t* Psb = (ushort_t*)(smem + 40960);
  ushort_t* Eb  = (ushort_t*)(smem + 51200);
  float*    Ohn = (float*)smem;   // [8][16][68] fl, 34816 B (epilogue overlay)

  const int n = blockIdx.y, q0 = blockIdx.x * 16;
  const int t = threadIdx.x;
  const int w = t >> 6, l = t & 63;
  const int lm = l & 15, quad = l >> 4;
  const float invs = 0.044194173824159216f;    // 1/sqrt(512)

  // Q fragments for this wave's 2 heads only
  short8 qf[4];
  {
    const ushort_t* qrow = Qb + ((size_t)(n * LQ + q0 + lm)) * 512 + (w * 2) * 64 + quad * 8;
    qf[0] = *(const short8*)(qrow);
    qf[1] = *(const short8*)(qrow + 32);
    qf[2] = *(const short8*)(qrow + 64);
    qf[3] = *(const short8*)(qrow + 96);
  }

  float tps[2][8], psl[2], tpo[2][8];
  #pragma unroll
  for (int gg = 0; gg < 2; ++gg) {
    const int g = w * 2 + gg;
    float ps = 0.f;
    #pragma unroll
    for (int h = 0; h < 8; ++h) {
      float tv = thpre[g * 8 + h] * invs;
      tps[gg][h] = tv;
      ps += tv * (1.0f / (float)(2 << h));     // slope_h = 2^-(h+1)
      tpo[gg][h] = thpost[g * 8 + h];
    }
    psl[gg] = ps;
  }

  float m_[2][4], z_[2][4];
  #pragma unroll
  for (int gg = 0; gg < 2; ++gg)
    #pragma unroll
    for (int r = 0; r < 4; ++r) { m_[gg][r] = -1e30f; z_[gg][r] = 0.f; }

  floatx4 o_[2][4];
  #pragma unroll
  for (int gg = 0; gg < 2; ++gg)
    #pragma unroll
    for (int ch = 0; ch < 4; ++ch) o_[gg][ch] = (floatx4){0.f, 0.f, 0.f, 0.f};

  // ---- global sources ----
  const ushort_t* kg  = Kb + ((size_t)(n * LP + lm)) * 512 + (w * 2) * 64 + quad * 8;
  // wave-private V staging: wave w stages exactly rows [w*128, w*128+128)
  const ushort_t* vgA = VT + ((size_t)(n * 512) + w * 128 + l) * LP;
  const ushort_t* vgB = VT + ((size_t)(n * 512) + w * 128 + 64 + l) * LP;

  short8 kfE[4], kfO[4], vX[4], vY[4];

  auto loadKg = [&](short8 (&r)[4], int step) {
    const ushort_t* p = kg + (size_t)step * 8192;
    r[0] = *(const short8*)(p);
    r[1] = *(const short8*)(p + 32);
    r[2] = *(const short8*)(p + 64);
    r[3] = *(const short8*)(p + 96);
  };
  auto loadVg = [&](short8 (&r)[4], int off) {
    r[0] = *(const short8*)(vgA + off); r[1] = *(const short8*)(vgA + off + 8);
    r[2] = *(const short8*)(vgB + off); r[3] = *(const short8*)(vgB + off + 8);
  };
  auto storeV = [&](short8 (&r)[4], int sub) {
    ushort_t* d0 = &Vt[(size_t)(w * 128 + l) * 40 + sub * 16];
    ushort_t* d1 = &Vt[(size_t)(w * 128 + 64 + l) * 40 + sub * 16];
    *(short8*)(d0)     = r[0]; *(short8*)(d0 + 8) = r[1];
    *(short8*)(d1)     = r[2]; *(short8*)(d1 + 8) = r[3];
  };

  // wave's 2-head QK^T -> bf16 E buffer [h][k=lm][q=quad*4+j]
  auto qktE = [&](short8 (&kf)[4], ushort_t* E) {
    #pragma unroll
    for (int hh = 0; hh < 2; ++hh) {
      floatx4 e = (floatx4){0.f, 0.f, 0.f, 0.f};
      e = __builtin_amdgcn_mfma_f32_16x16x32_bf16(qf[hh * 2 + 0], kf[hh * 2 + 0], e, 0, 0, 0);
      e = __builtin_amdgcn_mfma_f32_16x16x32_bf16(qf[hh * 2 + 1], kf[hh * 2 + 1], e, 0, 0, 0);
      ushort4 u;
      u.x = f2bf(e[0]); u.y = f2bf(e[1]); u.z = f2bf(e[2]); u.w = f2bf(e[3]);
      *(ushort4*)&E[(((w * 2 + hh) * 16 + lm)) * 20 + quad * 4] = u;
    }
  };

  // online softmax update for one pair (steps 2p, 2p+1). Reads E bufs
  // (2p)&3, (2p+1)&3; rescales o_/z_; writes Psb (bf16, both subs).
  auto online2 = [&](int p) {
    const ushort_t* Ea = Eb + ((2 * p) & 3) * 2560;
    const ushort_t* Ec = Eb + ((2 * p + 1) & 3) * 2560;
    float s0[2][4], s1[2][4];
    #pragma unroll
    for (int gg = 0; gg < 2; ++gg)
      #pragma unroll
      for (int r = 0; r < 4; ++r) { s0[gg][r] = 0.f; s1[gg][r] = 0.f; }
    #pragma unroll
    for (int h = 0; h < 8; ++h) {
      const ushort4 ua = *(const ushort4*)&Ea[(h * 16 + lm) * 20 + quad * 4];
      const ushort4 ub = *(const ushort4*)&Ec[(h * 16 + lm) * 20 + quad * 4];
      const float a_[4] = {bf2f(ua.x), bf2f(ua.y), bf2f(ua.z), bf2f(ua.w)};
      const float b_[4] = {bf2f(ub.x), bf2f(ub.y), bf2f(ub.z), bf2f(ub.w)};
      #pragma unroll
      for (int gg = 0; gg < 2; ++gg) {
        const float tv = tps[gg][h];
        #pragma unroll
        for (int r = 0; r < 4; ++r) {
          s0[gg][r] += tv * a_[r];
          s1[gg][r] += tv * b_[r];
        }
      }
    }
    const int k0 = 32 * p;
    float pm[2][4];
    #pragma unroll
    for (int r = 0; r < 4; ++r) {
      const float qpos = (float)(q0 + quad * 4 + r);
      const float d0 = fabsf(qpos - (float)(k0 + lm));
      const float d1 = fabsf(qpos - (float)(k0 + 16 + lm));
      #pragma unroll
      for (int gg = 0; gg < 2; ++gg) {
        s0[gg][r] -= d0 * psl[gg];
        s1[gg][r] -= d1 * psl[gg];
        pm[gg][r] = fmaxf(s0[gg][r], s1[gg][r]);
      }
    }
    #pragma unroll
    for (int off = 1; off < 16; off <<= 1)
      #pragma unroll
      for (int gg = 0; gg < 2; ++gg)
        #pragma unroll
        for (int r = 0; r < 4; ++r)
          pm[gg][r] = fmaxf(pm[gg][r], __shfl_xor(pm[gg][r], off));
    float sc[2][4];
    #pragma unroll
    for (int gg = 0; gg < 2; ++gg)
      #pragma unroll
      for (int r = 0; r < 4; ++r) {
        const float mn = fmaxf(m_[gg][r], pm[gg][r]);
        sc[gg][r] = __expf(m_[gg][r] - mn);
        const float p0 = __expf(s0[gg][r] - mn);
        const float p1 = __expf(s1[gg][r] - mn);
        z_[gg][r] = z_[gg][r] * sc[gg][r] + p0 + p1;
        m_[gg][r] = mn;
        ushort_t* prow = &Psb[((w * 2 + gg) * 16 + quad * 4 + r) * 40];
        prow[lm] = f2bf(p0);
        prow[16 + lm] = f2bf(p1);
      }
    #pragma unroll
    for (int gg = 0; gg < 2; ++gg)
      #pragma unroll
      for (int ch = 0; ch < 4; ++ch)
        #pragma unroll
        for (int r = 0; r < 4; ++r)
          o_[gg][ch][r] *= sc[gg][r];
  };

  // tail: single step 64 (persistent keys, no alibi). Reads E buf 0.
  auto online1 = [&]() {
    const ushort_t* Ea = Eb;   // (2*32)&3 == 0
    float s0[2][4];
    #pragma unroll
    for (int gg = 0; gg < 2; ++gg)
      #pragma unroll
      for (int r = 0; r < 4; ++r) s0[gg][r] = 0.f;
    #pragma unroll
    for (int h = 0; h < 8; ++h) {
      const ushort4 ua = *(const ushort4*)&Ea[(h * 16 + lm) * 20 + quad * 4];
      const float a_[4] = {bf2f(ua.x), bf2f(ua.y), bf2f(ua.z), bf2f(ua.w)};
      #pragma unroll
      for (int gg = 0; gg < 2; ++gg) {
        const float tv = tps[gg][h];
        #pragma unroll
        for (int r = 0; r < 4; ++r) s0[gg][r] += tv * a_[r];
      }
    }
    float pm[2][4];
    #pragma unroll
    for (int gg = 0; gg < 2; ++gg)
      #pragma unroll
      for (int r = 0; r < 4; ++r) pm[gg][r] = s0[gg][r];
    #pragma unroll
    for (int off = 1; off < 16; off <<= 1)
      #pragma unroll
      for (int gg = 0; gg < 2; ++gg)
        #pragma unroll
        for (int r = 0; r < 4; ++r)
          pm[gg][r] = fmaxf(pm[gg][r], __shfl_xor(pm[gg][r], off));
    float sc[2][4];
    #pragma unroll
    for (int gg = 0; gg < 2; ++gg)
      #pragma unroll
      for (int r = 0; r < 4; ++r) {
        const float mn = fmaxf(m_[gg][r], pm[gg][r]);
        sc[gg][r] = __expf(m_[gg][r] - mn);
        const float p0 = __expf(s0[gg][r] - mn);
        z_[gg][r] = z_[gg][r] * sc[gg][r] + p0;
        m_[gg][r] = mn;
        ushort_t* prow = &Psb[((w * 2 + gg) * 16 + quad * 4 + r) * 40];
        prow[lm] = f2bf(p0);
        prow[16 + lm] = 0;
      }
    #pragma unroll
    for (int gg = 0; gg < 2; ++gg)
      #pragma unroll
      for (int ch = 0; ch < 4; ++ch)
        #pragma unroll
        for (int r = 0; r < 4; ++r)
          o_[gg][ch][r] *= sc[gg][r];
  };

  // P·V for own 2 heads: A-frag = bf16 Psb row (bit-identical to v8's
  // f2bf-in-pv), B-frag from Vt (wave-private slice).
  auto pv = [&]() {
    #pragma unroll
    for (int gg = 0; gg < 2; ++gg) {
      const short8 pk = *(const short8*)&Psb[((w * 2 + gg) * 16 + lm) * 40 + quad * 8];
      #pragma unroll
      for (int ch = 0; ch < 4; ++ch) {
        const int d = (w * 2 + gg) * 64 + ch * 16 + lm;   // within wave slice
        const short8 vf = *(const short8*)&Vt[d * 40 + quad * 8];
        o_[gg][ch] = __builtin_amdgcn_mfma_f32_16x16x32_bf16(pk, vf, o_[gg][ch], 0, 0, 0);
      }
    }
  };

  // ---------------- single pass, one barrier per pair --------------------
  loadKg(kfE, 0);
  loadKg(kfO, 1);
  loadVg(vX, 0);
  loadVg(vY, 16);
  qktE(kfE, Eb + 0 * 2560);            // pair 0 -> bufs 0,1
  qktE(kfO, Eb + 1 * 2560);
  loadKg(kfE, 2);                      // pair 1 K
  loadKg(kfO, 3);
  __syncthreads();                     // E(pair 0) visible

  for (int p = 0; p < 32; ++p) {
    __builtin_amdgcn_s_setprio(1);
    if (p > 0) pv();                               // pair p-1 (Psb/Vt same-wave)
    qktE(kfE, Eb + ((2 * p + 2) & 3) * 2560);      // pair p+1 (p=31: tail step 64)
    if (p < 31) qktE(kfO, Eb + ((2 * p + 3) & 3) * 2560);
    __builtin_amdgcn_s_setprio(0);
    online2(p);                                    // reads E(pair p); writes Psb
    storeV(vX, 0);                                 // Vt <- pair p (after pv read)
    storeV(vY, 1);
    if (p < 30)       { loadKg(kfE, 2 * p + 4); loadKg(kfO, 2 * p + 5); }
    else if (p == 30) { loadKg(kfE, 64); }         // tail K
    loadVg(vX, 32 * (p + 1));                      // p=31 -> 1024 (tail, in-bounds)
    if (p < 31) loadVg(vY, 32 * (p + 1) + 16);
    __syncthreads();
  }
  // tail: step 64 (E buf 0 written in phase 31; vX holds tail V)
  pv();                                // pair 31
  online1();
  storeV(vX, 0);                       // tail V -> sub0; sub1 stale x P==0
  pv();                                // tail contribution

  // ---------------- epilogue: z combine, per-head normalize, head mix ----
  #pragma unroll
  for (int off = 1; off < 16; off <<= 1)
    #pragma unroll
    for (int gg = 0; gg < 2; ++gg)
      #pragma unroll
      for (int r = 0; r < 4; ++r)
        z_[gg][r] += __shfl_xor(z_[gg][r], off);
  #pragma unroll
  for (int gg = 0; gg < 2; ++gg)
    #pragma unroll
    for (int r = 0; r < 4; ++r) {
      const float zi = 1.0f / z_[gg][r];
      #pragma unroll
      for (int ch = 0; ch < 4; ++ch) o_[gg][ch][r] *= zi;
    }

  __syncthreads();    // all waves' LDS reads done; safe to overlay Ohn
  #pragma unroll
  for (int gg = 0; gg < 2; ++gg)
    #pragma unroll
    for (int ch = 0; ch < 4; ++ch)
      #pragma unroll
      for (int r = 0; r < 4; ++r)
        Ohn[(w * 2 + gg) * 1088 + (quad * 4 + r) * 68 + ch * 16 + lm] = o_[gg][ch][r];
  __syncthreads();

  float acc[2][4][4];
  #pragma unroll
  for (int gg = 0; gg < 2; ++gg)
    #pragma unroll
    for (int ch = 0; ch < 4; ++ch)
      #pragma unroll
      for (int r = 0; r < 4; ++r) acc[gg][ch][r] = 0.f;
  #pragma unroll
  for (int h = 0; h < 8; ++h) {
    #pragma unroll
    for (int ch = 0; ch < 4; ++ch)
      #pragma unroll
      for (int r = 0; r < 4; ++r) {
        const float ov = Ohn[h * 1088 + (quad * 4 + r) * 68 + ch * 16 + lm];
        acc[0][ch][r] += tpo[0][h] * ov;
        acc[1][ch][r] += tpo[1][h] * ov;
      }
  }

  #pragma unroll
  for (int gg = 0; gg < 2; ++gg)
    #pragma unroll
    for (int ch = 0; ch < 4; ++ch) {
      const int d = (w * 2 + gg) * 64 + ch * 16 + lm;
      #pragma unroll
      for (int r = 0; r < 4; ++r)
        aob[((size_t)(n * LQ + q0 + quad * 4 + r)) * 512 + d] = f2bf(acc[gg][ch][r]);
    }
}

// ---------------------------------------------------------------------------
// swiglu: h = silu(h1+b1)*(h2+b2), raw [8192][4096] bf16 -> padded bf16
// vectorized: one short8 per thread (2048 cols / 256 threads = 8)
// ---------------------------------------------------------------------------
__global__ __launch_bounds__(256) void swiglu_kernel(
    const ushort_t* __restrict__ hraw, const float* __restrict__ bias,
    ushort_t* __restrict__ hpad)
{
  const int tok = blockIdx.x;
  const int n = tok >> 10, l = tok & 1023;
  const int c = threadIdx.x * 8;
  const size_t src = (size_t)tok * 4096 + c;
  const size_t dst = ((size_t)n * 1026 + l + 1) * 2048 + c;
  const short8 h1v = *(const short8*)&hraw[src];
  const short8 h2v = *(const short8*)&hraw[src + 2048];
  const float4 b1a = *(const float4*)&bias[c];
  const float4 b1b = *(const float4*)&bias[c + 4];
  const float4 b2a = *(const float4*)&bias[2048 + c];
  const float4 b2b = *(const float4*)&bias[2048 + c + 4];
  const float bb1[8] = {b1a.x, b1a.y, b1a.z, b1a.w, b1b.x, b1b.y, b1b.z, b1b.w};
  const float bb2[8] = {b2a.x, b2a.y, b2a.z, b2a.w, b2b.x, b2b.y, b2b.z, b2b.w};
  short8 o;
  #pragma unroll
  for (int j = 0; j < 8; ++j) {
    const float h1 = bf2f((ushort_t)h1v[j]) + bb1[j];
    const float h2 = bf2f((ushort_t)h2v[j]) + bb2[j];
    const float s = h1 / (1.f + __expf(-h1));
    o[j] = (short)f2bf(s * h2);
  }
  *(short8*)&hpad[dst] = o;
}

__global__ __launch_bounds__(256) void zero_pads_kernel(
    ushort_t* __restrict__ x1b, ushort_t* __restrict__ hpad)
{
  const int b = blockIdx.x;
  const int n = b >> 1, side = b & 1;
  const size_t r = (size_t)n * 1026 + side * 1025;
  ushort2 z; z.x = 0; z.y = 0;
  *(ushort2*)&x1b[r * 512 + threadIdx.x * 2] = z;
  #pragma unroll
  for (int i = 0; i < 4; ++i)
    *(ushort2*)&hpad[r * 2048 + (threadIdx.x + 256 * i) * 2] = z;
}

// ---------------------------------------------------------------------------
// LayerNorm (fp32) + optional bf16 padded copy
// ---------------------------------------------------------------------------
__global__ __launch_bounds__(256) void ln_kernel(
    const float* __restrict__ in, const float* __restrict__ res,
    const float* __restrict__ g, const float* __restrict__ b,
    float* __restrict__ outp, ushort_t* __restrict__ bfout)
{
  const int w = threadIdx.x >> 6, lane = threadIdx.x & 63;
  const int tok = blockIdx.x * 4 + w;
  const size_t base = (size_t)tok * CH;
  float4 v0 = *(const float4*)&in[base + (lane << 2)];
  float4 v1 = *(const float4*)&in[base + 256 + (lane << 2)];
  if (res != nullptr) {
    float4 r0 = *(const float4*)&res[base + (lane << 2)];
    float4 r1 = *(const float4*)&res[base + 256 + (lane << 2)];
    v0.x += r0.x; v0.y += r0.y; v0.z += r0.z; v0.w += r0.w;
    v1.x += r1.x; v1.y += r1.y; v1.z += r1.z; v1.w += r1.w;
  }
  float s = v0.x + v0.y + v0.z + v0.w + v1.x + v1.y + v1.z + v1.w;
  #pragma unroll
  for (int off = 32; off > 0; off >>= 1) s += __shfl_xor(s, off);
  const float mu = s * (1.f / 512.f);
  float d0 = v0.x - mu, d1 = v0.y - mu, d2 = v0.z - mu, d3 = v0.w - mu;
  float d4 = v1.x - mu, d5 = v1.y - mu, d6 = v1.z - mu, d7 = v1.w - mu;
  float vs = d0*d0 + d1*d1 + d2*d2 + d3*d3 + d4*d4 + d5*d5 + d6*d6 + d7*d7;
  #pragma unroll
  for (int off = 32; off > 0; off >>= 1) vs += __shfl_xor(vs, off);
  const float r = rsqrtf(vs * (1.f / 512.f) + 1e-5f);
  float4 ga = *(const float4*)&g[(lane << 2)];
  float4 gb = *(const float4*)&g[256 + (lane << 2)];
  float4 ba = *(const float4*)&b[(lane << 2)];
  float4 bb = *(const float4*)&b[256 + (lane << 2)];
  float4 o0, o1;
  o0.x = d0 * r * ga.x + ba.x; o0.y = d1 * r * ga.y + ba.y;
  o0.z = d2 * r * ga.z + ba.z; o0.w = d3 * r * ga.w + ba.w;
  o1.x = d4 * r * gb.x + bb.x; o1.y = d5 * r * gb.y + bb.y;
  o1.z = d6 * r * gb.z + bb.z; o1.w = d7 * r * gb.w + bb.w;
  *(float4*)&outp[base + (lane << 2)] = o0;
  *(float4*)&outp[base + 256 + (lane << 2)] = o1;
  if (bfout != nullptr) {
    const int n = tok >> 10, ll = tok & 1023;
    const size_t bb2 = ((size_t)n * 1026 + ll + 1) * 512;
    ushort4 u0 = make_ushort4(f2bf(o0.x), f2bf(o0.y), f2bf(o0.z), f2bf(o0.w));
    ushort4 u1 = make_ushort4(f2bf(o1.x), f2bf(o1.y), f2bf(o1.z), f2bf(o1.w));
    *(ushort4*)&bfout[bb2 + (lane << 2)] = u0;
    *(ushort4*)&bfout[bb2 + 256 + (lane << 2)] = u1;
  }
}

// ---------------------------------------------------------------------------
extern "C" void kernel_launch(void* const* d_in, const int* in_sizes, int n_in,
                              void* d_out, int out_size, void* d_ws, size_t ws_size,
                              hipStream_t stream)
{
  (void)in_sizes; (void)n_in; (void)out_size; (void)ws_size;
  const float* x      = (const float*)d_in[0];
  const float* Wq     = (const float*)d_in[1];
  const float* Wk     = (const float*)d_in[2];
  const float* Wv     = (const float*)d_in[3];
  const float* Wo     = (const float*)d_in[4];
  const float* bo     = (const float*)d_in[5];
  const float* th_pre = (const float*)d_in[6];
  const float* th_post= (const float*)d_in[7];
  const float* p_keys = (const float*)d_in[8];
  const float* p_vals = (const float*)d_in[9];
  const float* c1w    = (const float*)d_in[10];
  const float* c1b    = (const float*)d_in[11];
  const float* c2w    = (const float*)d_in[12];
  const float* c2b    = (const float*)d_in[13];
  const float* ln1g   = (const float*)d_in[14];
  const float* ln1b   = (const float*)d_in[15];
  const float* ln2g   = (const float*)d_in[16];
  const float* ln2b   = (const float*)d_in[17];

  float* ws  = (float*)d_ws;
  float* out = (float*)d_out;

  ushort_t* Qb   = (ushort_t*)(ws + O_QB);
  ushort_t* Kb   = (ushort_t*)(ws + O_KB);
  ushort_t* Vb   = (ushort_t*)(ws + O_VB);
  ushort_t* VT   = (ushort_t*)(ws + O_VT);
  ushort_t* aob  = (ushort_t*)(ws + O_AOB);
  float*    abf  = ws + O_AF;
  ushort_t* x1b  = (ushort_t*)(ws + O_X1B);
  ushort_t* hpad = (ushort_t*)(ws + O_HPAD);
  ushort_t* hraw = (ushort_t*)ws;         // overlays dead attn buffers
  float*    pk4  = ws;                    // conv2 partials [4][8192*512], overlays dead hraw/attn/abf
  ushort_t* w1p  = (ushort_t*)(ws + O_W1);
  ushort_t* w2p  = (ushort_t*)(ws + O_W2);
  ushort_t* wop  = (ushort_t*)(ws + O_WO);

  pack_bf16_kernel<<<4096, 256, 0, stream>>>(c1w, w1p, 1536, 3, 9);
  pack_bf16_kernel<<<512,  256, 0, stream>>>(c2w, w2p, 6144, 3, 11);
  pack_bf16_kernel<<<512,  256, 0, stream>>>(Wo,  wop, 512,  1, 9);

  qkv_mfma<<<dim3(128, 3), 256, 0, stream>>>(x, Wq, Wk, Wv, Qb, Kb, Vb);
  persist_kernel<<<256, 256, 0, stream>>>(p_keys, p_vals, Kb, Vb);
  vtrans_kernel<<<dim3(65, 8), 256, 0, stream>>>(Vb, VT);

  attn_mfma<<<dim3(64, 8), 256, 0, stream>>>(Qb, Kb, VT, th_pre, th_post, aob);

  // Wo: M=8192 N=512 K=512, +bias +residual(x) -> abf fp32
  mfma_gemm<2><<<dim3(64, 4), 256, 0, stream>>>(
      aob, wop, 512, 1024 * 512, 512, 512, bo, x, abf, nullptr);

  ln_kernel<<<2048, 256, 0, stream>>>(abf, nullptr, ln1g, ln1b, out, x1b);
  zero_pads_kernel<<<16, 256, 0, stream>>>(x1b, hpad);

  // conv1: M=8192 N=4096 K=1536 -> hraw bf16
  mfma_gemm<0><<<dim3(64, 32), 256, 0, stream>>>(
      x1b, w1p, 1536, 1026 * 512, 512, 4096, nullptr, nullptr, nullptr, hraw);

  swiglu_kernel<<<8192, 256, 0, stream>>>(hraw, c1b, hpad);

  // conv2: M=8192 N=512 K=6144, split-K=4 -> partials; ksum adds bias
  mfma_gemm<3><<<dim3(64, 4, 4), 256, 0, stream>>>(
      hpad, w2p, 6144, 1026 * 2048, 2048, 512, nullptr, nullptr, pk4, nullptr);
  ksum_kernel<<<4096, 256, 0, stream>>>(pk4, c2b);

  ln_kernel<<<2048, 256, 0, stream>>>(pk4, out, ln2g, ln2b, out, nullptr);
}